// Round 19
// baseline (672.932 us; speedup 1.0000x reference)
//
#include <hip/hip_runtime.h>

typedef short bf16x8 __attribute__((ext_vector_type(8)));
typedef _Float16 f16x8 __attribute__((ext_vector_type(8)));
typedef float f32x4 __attribute__((ext_vector_type(4)));

__device__ __forceinline__ short f2h(float f) {
  _Float16 h = (_Float16)f;
  return __builtin_bit_cast(short, h);
}
__device__ __forceinline__ float h2f(short s) {
  return (float)__builtin_bit_cast(_Float16, s);
}

__device__ __forceinline__ void gload16(const void* g, void* lds) {
  __builtin_amdgcn_global_load_lds(
      (const __attribute__((address_space(1))) unsigned*)g,
      (__attribute__((address_space(3))) unsigned*)lds, 16, 0, 0);
}

// ---------------------------------------------------------------------------
// r6/r14 structure (142 us proj, 0 bank conflicts; 7 schedule variants all
// converge at 950-970 TF -> frozen) + T1 XCD swizzle (r17: FETCH 270->100 MB,
// -38 us). RES=1: fp32 residual; RES=2: f16 residual (halves z residual HBM
// traffic; rounding delta ~2e-3, used only when ws_size permits un-aliased
// layout).
// ---------------------------------------------------------------------------
template <int NF, int K, int OMODE, int BIAS_MODE, int RES>
__global__ __launch_bounds__(512, 2) void gemm256(
    const short* __restrict__ A, int lda, long sA,
    const short* __restrict__ B, int ldb, long sB,
    void* __restrict__ Cv, int ldc, long sC,
    const float* __restrict__ bias, const void* __restrict__ resid, long sR) {
  constexpr int BN = NF * 64;
  constexpr int BNB = BN * 128;  // B-tile bytes per buffer
  constexpr int NT = K / 64;
  __shared__ char lds[65536 + 2 * BNB];  // A: 2x32KB, B: 2xBNB

  A += (size_t)blockIdx.z * sA;
  B += (size_t)blockIdx.z * sB;
  char* Cb = (char*)Cv + (size_t)blockIdx.z * sC * (OMODE == 0 ? 4 : 2);
  const float* resf = nullptr;
  const short* resh = nullptr;
  if (RES == 1) resf = (const float*)resid + (size_t)blockIdx.z * sR;
  if (RES == 2) resh = (const short*)resid + (size_t)blockIdx.z * sR;

  // T1 XCD swizzle (nwg % 8 == 0 for every launch below)
  const int nwg = gridDim.x * gridDim.y;
  const int wg = blockIdx.x + gridDim.x * blockIdx.y;
  const int swzid = (wg & 7) * (nwg >> 3) + (wg >> 3);
  const int bxi = swzid % gridDim.x, byi = swzid / gridDim.x;

  const int tid = threadIdx.x;
  const int wid = tid >> 6, lane = tid & 63;
  const int wr = wid >> 2, wc = wid & 3;  // wave grid 2 (M) x 4 (N)
  const int fr = lane & 15, fq = lane >> 4;
  const size_t bm = (size_t)byi * 256;
  const size_t bn = (size_t)bxi * BN;

  // staging: per chunk 64 rows x 128 B; thread covers row srow, 16 B at scolS
  const int srow = wid * 8 + (lane >> 3);                   // 0..63
  const int scolS = ((lane & 7) * 16) ^ ((srow & 7) << 4);  // inv-swizzled src
  const char* Ag = (const char*)A;
  const char* Bg = (const char*)B;

  // ds_read byte offsets (ks=0, buffer 0); row&7 == fr&7 for all fragments
  const int swz = (fr & 7) << 4;
  int aoff[8], boff[NF];
#pragma unroll
  for (int m = 0; m < 8; m++)
    aoff[m] = (wr * 128 + m * 16 + fr) * 128 + ((fq * 16) ^ swz);
#pragma unroll
  for (int n = 0; n < NF; n++)
    boff[n] = (wc * NF * 16 + n * 16 + fr) * 128 + ((fq * 16) ^ swz);

  f32x4 acc[8][NF];
#pragma unroll
  for (int m = 0; m < 8; m++)
#pragma unroll
    for (int n = 0; n < NF; n++) acc[m][n] = (f32x4){0.f, 0.f, 0.f, 0.f};

  auto stage = [&](int t, int d) {
    const int ktb = t * 128;  // byte offset along K
#pragma unroll
    for (int c = 0; c < 4; ++c)
      gload16(Ag + ((size_t)(bm + c * 64 + srow) * lda) * 2 + ktb + scolS,
              &lds[d * 32768 + c * 8192 + wid * 1024]);
#pragma unroll
    for (int c = 0; c < NF; ++c)
      gload16(Bg + ((size_t)(bn + c * 64 + srow) * ldb) * 2 + ktb + scolS,
              &lds[65536 + d * BNB + c * 8192 + wid * 1024]);
  };

  stage(0, 0);
  int cur = 0;
#pragma unroll 2
  for (int t = 0; t < NT; ++t) {
    if (t + 1 < NT) stage(t + 1, cur ^ 1);
    __builtin_amdgcn_sched_barrier(0);
    if (t + 1 < NT) {
      if constexpr (NF == 4)
        asm volatile("s_waitcnt vmcnt(8)");  // tile t done; t+1's 8 in flight
      else
        asm volatile("s_waitcnt vmcnt(6)");
    } else {
      asm volatile("s_waitcnt vmcnt(0)");
    }
    __builtin_amdgcn_sched_barrier(0);
    __builtin_amdgcn_s_barrier();  // all waves see buf[cur] full
    __builtin_amdgcn_sched_barrier(0);
    {
      const int dA = cur * 32768, dB = 65536 + cur * BNB;
#pragma unroll
      for (int ks = 0; ks < 2; ++ks) {
        f16x8 ar[8], br[NF];
#pragma unroll
        for (int m = 0; m < 8; m++)
          ar[m] = *(const f16x8*)&lds[dA + (aoff[m] ^ (ks << 6))];
#pragma unroll
        for (int n = 0; n < NF; n++)
          br[n] = *(const f16x8*)&lds[dB + (boff[n] ^ (ks << 6))];
#pragma unroll
        for (int m = 0; m < 8; m++)
#pragma unroll
          for (int n = 0; n < NF; n++)
            acc[m][n] = __builtin_amdgcn_mfma_f32_16x16x32_f16(
                ar[m], br[n], acc[m][n], 0, 0, 0);
      }
    }
    __builtin_amdgcn_sched_barrier(0);
    __builtin_amdgcn_s_barrier();  // buf[cur] free for overwrite next iter
    __builtin_amdgcn_sched_barrier(0);
    cur ^= 1;
  }

#pragma unroll
  for (int m = 0; m < 8; m++) {
    const size_t row0 = bm + wr * 128 + m * 16 + fq * 4;
#pragma unroll
    for (int n = 0; n < NF; n++) {
      const size_t col = bn + wc * NF * 16 + n * 16 + fr;
      float bcol = (BIAS_MODE == 1) ? bias[col] : 0.f;
#pragma unroll
      for (int r = 0; r < 4; r++) {
        float val = acc[m][n][r];
        const size_t row = row0 + r;
        const size_t idx = row * (size_t)ldc + col;
        if (BIAS_MODE == 1) val += bcol;
        if (BIAS_MODE == 2) val += bias[row];
        if (RES == 1) val += resf[idx];
        if (RES == 2) val += h2f(resh[idx]);
        if (OMODE == 0)
          ((float*)Cb)[idx] = val;
        else
          ((short*)Cb)[idx] = f2h(val);
      }
    }
  }
}

__global__ __launch_bounds__(256) void cvt_f32_f16(const float* __restrict__ s,
                                                   short* __restrict__ d, int n) {
  int i = (blockIdx.x * 256 + threadIdx.x) * 8;
  if (i >= n) return;
  const float4 a = *(const float4*)(s + i);
  const float4 b = *(const float4*)(s + i + 4);
  bf16x8 o;
  o[0] = f2h(a.x); o[1] = f2h(a.y); o[2] = f2h(a.z); o[3] = f2h(a.w);
  o[4] = f2h(b.x); o[5] = f2h(b.y); o[6] = f2h(b.z); o[7] = f2h(b.w);
  *(bf16x8*)(d + i) = o;
}

// merged weight conversion: 4 x (2M f32 -> f16) + theta_b|phi_b bias concat.
__global__ __launch_bounds__(256) void cvt_weights(
    const float* __restrict__ thw, const float* __restrict__ phw,
    const float* __restrict__ gw, const float* __restrict__ Ww,
    short* __restrict__ wcat, short* __restrict__ gwb, short* __restrict__ wWb,
    const float* __restrict__ thb, const float* __restrict__ phb,
    float* __restrict__ bc) {
  const int b = blockIdx.x;  // 0..4095
  const int seg = b >> 10, ib = b & 1023;
  const float* s;
  short* d;
  if (seg == 0) { s = thw; d = wcat; }
  else if (seg == 1) { s = phw; d = wcat + 2097152; }
  else if (seg == 2) { s = gw; d = gwb; }
  else { s = Ww; d = wWb; }
  const int i = (ib * 256 + threadIdx.x) * 8;
  const float4 a = *(const float4*)(s + i);
  const float4 v = *(const float4*)(s + i + 4);
  bf16x8 o;
  o[0] = f2h(a.x); o[1] = f2h(a.y); o[2] = f2h(a.z); o[3] = f2h(a.w);
  o[4] = f2h(v.x); o[5] = f2h(v.y); o[6] = f2h(v.z); o[7] = f2h(v.w);
  *(bf16x8*)(d + i) = o;
  if (b == 0) {  // bias concat: 256 thr x 8 f32 = 2048
    const int j = threadIdx.x * 8;
#pragma unroll
    for (int k = 0; k < 8; ++k) {
      const int jj = j + k;
      bc[jj] = (jj < 1024) ? thb[jj] : phb[jj - 1024];
    }
  }
}

// one block per row of 4096 f16 scores; fp32 softmax; in-place f16 probs
__global__ __launch_bounds__(256) void softmax_rows(short* __restrict__ S) {
  const size_t row = blockIdx.x;
  short* rp = S + row * 4096;
  const int tid = threadIdx.x;
  const int lane = tid & 63, wid = tid >> 6;
  float v[16];
#pragma unroll
  for (int c = 0; c < 2; c++) {
    bf16x8 xv = *(const bf16x8*)(rp + (c * 256 + tid) * 8);
#pragma unroll
    for (int j = 0; j < 8; j++) v[c * 8 + j] = h2f(xv[j]);
  }
  float m = v[0];
#pragma unroll
  for (int i = 1; i < 16; i++) m = fmaxf(m, v[i]);
#pragma unroll
  for (int off = 32; off >= 1; off >>= 1) m = fmaxf(m, __shfl_xor(m, off));
  __shared__ float red[8];
  if (lane == 0) red[wid] = m;
  __syncthreads();
  m = fmaxf(fmaxf(red[0], red[1]), fmaxf(red[2], red[3]));
  float s = 0.f;
#pragma unroll
  for (int i = 0; i < 16; i++) {
    v[i] = __expf(v[i] - m);
    s += v[i];
  }
#pragma unroll
  for (int off = 32; off >= 1; off >>= 1) s += __shfl_xor(s, off);
  if (lane == 0) red[4 + wid] = s;
  __syncthreads();
  s = (red[4] + red[5]) + (red[6] + red[7]);
  const float rs = 1.0f / s;
#pragma unroll
  for (int c = 0; c < 2; c++) {
    bf16x8 o;
#pragma unroll
    for (int j = 0; j < 8; j++) o[j] = f2h(v[c * 8 + j] * rs);
    *(bf16x8*)(rp + (c * 256 + tid) * 8) = o;
  }
}

extern "C" void kernel_launch(void* const* d_in, const int* in_sizes, int n_in,
                              void* d_out, int out_size, void* d_ws,
                              size_t ws_size, hipStream_t stream) {
  const float* x   = (const float*)d_in[0];
  const float* thw = (const float*)d_in[1];
  const float* thb = (const float*)d_in[2];
  const float* phw = (const float*)d_in[3];
  const float* phb = (const float*)d_in[4];
  const float* gw  = (const float*)d_in[5];
  const float* gbi = (const float*)d_in[6];
  const float* Ww  = (const float*)d_in[7];
  const float* Wb  = (const float*)d_in[8];
  float* out = (float*)d_out;

  // B=4, N=4096, D=2048, E=1024.
  char* ws = (char*)d_ws;
  short* xf   = (short*)(ws);                // 67,108,864 B (16384x2048 f16)
  short* wcat = (short*)(ws + 67108864);     //  8,388,608 B (theta|phi 2048x2048)
  short* gwb  = (short*)(ws + 75497472);     //  4,194,304 B (1024x2048)
  short* wWb  = (short*)(ws + 79691776);     //  4,194,304 B (2048x1024)
  float* bc   = (float*)(ws + 83886080);     //  8,192 B (theta_b|phi_b)
  short* tpf  = (short*)(ws + 83894272);     // 67,108,864 B (theta|phi; later y)
  short* gT   = (short*)(ws + 151003136);    // 33,554,432 B (4x1024x4096)
  // sc placement (2x4096x4096 f16 = 67,108,864 B per batch-pair):
  //  big-ws path: fresh region after gT -> xf stays intact -> z-GEMM reads
  //               residual from xf as f16 (halves its residual HBM traffic).
  //  small-ws path (== proven r17 layout): sc overlays xf (dead after gT);
  //               z-GEMM reads fp32 x as residual.
  const bool bigws = ws_size >= 251666432ULL;
  short* sc = bigws ? (short*)(ws + 184557568) : (short*)(ws);

  // 1) fp32 -> f16 conversions (x big pass + single merged weight pass)
  cvt_f32_f16<<<16384, 256, 0, stream>>>(x, xf, 33554432);
  cvt_weights<<<4096, 256, 0, stream>>>(thw, phw, gw, Ww, wcat, gwb, wWb, thb,
                                        phb, bc);

  // 2) proj: [theta|phi] = x @ wcat^T + bias   (16384 x 2048, K=2048)
  gemm256<4, 2048, 1, 1, 0><<<dim3(8, 64, 1), 512, 0, stream>>>(
      xf, 2048, 0L, wcat, 2048, 0L, tpf, 2048, 0L, bc, nullptr, 0L);

  // 3) gT[b] = g_w @ x_b^T + g_b[row]   (1024 x 4096 per batch, K=2048)
  gemm256<4, 2048, 1, 2, 0><<<dim3(16, 4, 4), 512, 0, stream>>>(
      gwb, 2048, 0L, xf, 2048, 8388608L, gT, 4096, 4194304L, gbi, nullptr, 0L);

  // 4) per batch-PAIR p: scores(z=2) -> softmax -> y(z=2) -> z(z=2)
  //    y overwrites consumed theta/phi.
  for (int p = 0; p < 2; ++p) {
    const short* tp = tpf + (size_t)p * 16777216;
    gemm256<4, 1024, 1, 0, 0><<<dim3(16, 16, 2), 512, 0, stream>>>(
        tp, 2048, 8388608L, tp + 1024, 2048, 8388608L,
        sc, 4096, 16777216L, nullptr, nullptr, 0L);
    softmax_rows<<<8192, 256, 0, stream>>>(sc);
    short* yp = tpf + (size_t)p * 16777216;  // pair-p theta/phi now dead
    gemm256<2, 4096, 1, 0, 0><<<dim3(8, 16, 2), 512, 0, stream>>>(
        sc, 4096, 16777216L, gT + (size_t)p * 8388608, 4096, 4194304L,
        yp, 1024, 4194304L, nullptr, nullptr, 0L);
    if (bigws) {
      gemm256<4, 1024, 0, 1, 2><<<dim3(8, 16, 2), 512, 0, stream>>>(
          yp, 1024, 4194304L, wWb, 1024, 0L,
          out + (size_t)p * 16777216, 2048, 8388608L,
          Wb, xf + (size_t)p * 16777216, 8388608L);
    } else {
      gemm256<4, 1024, 0, 1, 1><<<dim3(8, 16, 2), 512, 0, stream>>>(
          yp, 1024, 4194304L, wWb, 1024, 0L,
          out + (size_t)p * 16777216, 2048, 8388608L,
          Wb, x + (size_t)p * 16777216, 8388608L);
    }
  }
}

// Round 20
// 659.244 us; speedup vs baseline: 1.0208x; 1.0208x over previous
//
#include <hip/hip_runtime.h>

typedef short bf16x8 __attribute__((ext_vector_type(8)));
typedef _Float16 f16x8 __attribute__((ext_vector_type(8)));
typedef float f32x4 __attribute__((ext_vector_type(4)));

__device__ __forceinline__ short f2h(float f) {
  _Float16 h = (_Float16)f;
  return __builtin_bit_cast(short, h);
}
__device__ __forceinline__ float h2f(short s) {
  return (float)__builtin_bit_cast(_Float16, s);
}

__device__ __forceinline__ void gload16(const void* g, void* lds) {
  __builtin_amdgcn_global_load_lds(
      (const __attribute__((address_space(1))) unsigned*)g,
      (__attribute__((address_space(3))) unsigned*)lds, 16, 0, 0);
}

// ---------------------------------------------------------------------------
// FINAL (session-best, r18 == 661.2 us): r6 GEMM structure (256xBN, BK=64,
// 8 waves 2Mx4N, dbuf LDS, 0-conflict both-sides swizzle, counted vmcnt) +
// T1 XCD block swizzle (FETCH 270->100 MB) + merged weight cvt.
// Exhausted levers: 7 schedule restructures (r7/r8/r11/r12/r13/r16) all
// converge at the same ~950-970 TF core; f16-residual via un-aliased sc
// (r19) regressed — 251 MB ws footprint blew L3. Aliased layout kept.
// ---------------------------------------------------------------------------
template <int NF, int K, int OMODE, int BIAS_MODE, int RES>
__global__ __launch_bounds__(512, 2) void gemm256(
    const short* __restrict__ A, int lda, long sA,
    const short* __restrict__ B, int ldb, long sB,
    void* __restrict__ Cv, int ldc, long sC,
    const float* __restrict__ bias, const float* __restrict__ resid, long sR) {
  constexpr int BN = NF * 64;
  constexpr int BNB = BN * 128;  // B-tile bytes per buffer
  constexpr int NT = K / 64;
  __shared__ char lds[65536 + 2 * BNB];  // A: 2x32KB, B: 2xBNB

  A += (size_t)blockIdx.z * sA;
  B += (size_t)blockIdx.z * sB;
  char* Cb = (char*)Cv + (size_t)blockIdx.z * sC * (OMODE == 0 ? 4 : 2);
  const float* res = resid ? resid + (size_t)blockIdx.z * sR : nullptr;

  // T1 XCD swizzle (nwg % 8 == 0 for every launch below)
  const int nwg = gridDim.x * gridDim.y;
  const int wg = blockIdx.x + gridDim.x * blockIdx.y;
  const int swzid = (wg & 7) * (nwg >> 3) + (wg >> 3);
  const int bxi = swzid % gridDim.x, byi = swzid / gridDim.x;

  const int tid = threadIdx.x;
  const int wid = tid >> 6, lane = tid & 63;
  const int wr = wid >> 2, wc = wid & 3;  // wave grid 2 (M) x 4 (N)
  const int fr = lane & 15, fq = lane >> 4;
  const size_t bm = (size_t)byi * 256;
  const size_t bn = (size_t)bxi * BN;

  // staging: per chunk 64 rows x 128 B; thread covers row srow, 16 B at scolS
  const int srow = wid * 8 + (lane >> 3);                   // 0..63
  const int scolS = ((lane & 7) * 16) ^ ((srow & 7) << 4);  // inv-swizzled src
  const char* Ag = (const char*)A;
  const char* Bg = (const char*)B;

  // ds_read byte offsets (ks=0, buffer 0); row&7 == fr&7 for all fragments
  const int swz = (fr & 7) << 4;
  int aoff[8], boff[NF];
#pragma unroll
  for (int m = 0; m < 8; m++)
    aoff[m] = (wr * 128 + m * 16 + fr) * 128 + ((fq * 16) ^ swz);
#pragma unroll
  for (int n = 0; n < NF; n++)
    boff[n] = (wc * NF * 16 + n * 16 + fr) * 128 + ((fq * 16) ^ swz);

  f32x4 acc[8][NF];
#pragma unroll
  for (int m = 0; m < 8; m++)
#pragma unroll
    for (int n = 0; n < NF; n++) acc[m][n] = (f32x4){0.f, 0.f, 0.f, 0.f};

  auto stage = [&](int t, int d) {
    const int ktb = t * 128;  // byte offset along K
#pragma unroll
    for (int c = 0; c < 4; ++c)
      gload16(Ag + ((size_t)(bm + c * 64 + srow) * lda) * 2 + ktb + scolS,
              &lds[d * 32768 + c * 8192 + wid * 1024]);
#pragma unroll
    for (int c = 0; c < NF; ++c)
      gload16(Bg + ((size_t)(bn + c * 64 + srow) * ldb) * 2 + ktb + scolS,
              &lds[65536 + d * BNB + c * 8192 + wid * 1024]);
  };

  stage(0, 0);
  int cur = 0;
#pragma unroll 2
  for (int t = 0; t < NT; ++t) {
    if (t + 1 < NT) stage(t + 1, cur ^ 1);
    __builtin_amdgcn_sched_barrier(0);
    if (t + 1 < NT) {
      if constexpr (NF == 4)
        asm volatile("s_waitcnt vmcnt(8)");  // tile t done; t+1's 8 in flight
      else
        asm volatile("s_waitcnt vmcnt(6)");
    } else {
      asm volatile("s_waitcnt vmcnt(0)");
    }
    __builtin_amdgcn_sched_barrier(0);
    __builtin_amdgcn_s_barrier();  // all waves see buf[cur] full
    __builtin_amdgcn_sched_barrier(0);
    {
      const int dA = cur * 32768, dB = 65536 + cur * BNB;
#pragma unroll
      for (int ks = 0; ks < 2; ++ks) {
        f16x8 ar[8], br[NF];
#pragma unroll
        for (int m = 0; m < 8; m++)
          ar[m] = *(const f16x8*)&lds[dA + (aoff[m] ^ (ks << 6))];
#pragma unroll
        for (int n = 0; n < NF; n++)
          br[n] = *(const f16x8*)&lds[dB + (boff[n] ^ (ks << 6))];
#pragma unroll
        for (int m = 0; m < 8; m++)
#pragma unroll
          for (int n = 0; n < NF; n++)
            acc[m][n] = __builtin_amdgcn_mfma_f32_16x16x32_f16(
                ar[m], br[n], acc[m][n], 0, 0, 0);
      }
    }
    __builtin_amdgcn_sched_barrier(0);
    __builtin_amdgcn_s_barrier();  // buf[cur] free for overwrite next iter
    __builtin_amdgcn_sched_barrier(0);
    cur ^= 1;
  }

#pragma unroll
  for (int m = 0; m < 8; m++) {
    const size_t row0 = bm + wr * 128 + m * 16 + fq * 4;
#pragma unroll
    for (int n = 0; n < NF; n++) {
      const size_t col = bn + wc * NF * 16 + n * 16 + fr;
      float bcol = (BIAS_MODE == 1) ? bias[col] : 0.f;
#pragma unroll
      for (int r = 0; r < 4; r++) {
        float val = acc[m][n][r];
        const size_t row = row0 + r;
        const size_t idx = row * (size_t)ldc + col;
        if (BIAS_MODE == 1) val += bcol;
        if (BIAS_MODE == 2) val += bias[row];
        if (RES) val += res[idx];
        if (OMODE == 0)
          ((float*)Cb)[idx] = val;
        else
          ((short*)Cb)[idx] = f2h(val);
      }
    }
  }
}

__global__ __launch_bounds__(256) void cvt_f32_f16(const float* __restrict__ s,
                                                   short* __restrict__ d, int n) {
  int i = (blockIdx.x * 256 + threadIdx.x) * 8;
  if (i >= n) return;
  const float4 a = *(const float4*)(s + i);
  const float4 b = *(const float4*)(s + i + 4);
  bf16x8 o;
  o[0] = f2h(a.x); o[1] = f2h(a.y); o[2] = f2h(a.z); o[3] = f2h(a.w);
  o[4] = f2h(b.x); o[5] = f2h(b.y); o[6] = f2h(b.z); o[7] = f2h(b.w);
  *(bf16x8*)(d + i) = o;
}

// merged weight conversion: 4 x (2M f32 -> f16) + theta_b|phi_b bias concat.
__global__ __launch_bounds__(256) void cvt_weights(
    const float* __restrict__ thw, const float* __restrict__ phw,
    const float* __restrict__ gw, const float* __restrict__ Ww,
    short* __restrict__ wcat, short* __restrict__ gwb, short* __restrict__ wWb,
    const float* __restrict__ thb, const float* __restrict__ phb,
    float* __restrict__ bc) {
  const int b = blockIdx.x;  // 0..4095
  const int seg = b >> 10, ib = b & 1023;
  const float* s;
  short* d;
  if (seg == 0) { s = thw; d = wcat; }
  else if (seg == 1) { s = phw; d = wcat + 2097152; }
  else if (seg == 2) { s = gw; d = gwb; }
  else { s = Ww; d = wWb; }
  const int i = (ib * 256 + threadIdx.x) * 8;
  const float4 a = *(const float4*)(s + i);
  const float4 v = *(const float4*)(s + i + 4);
  bf16x8 o;
  o[0] = f2h(a.x); o[1] = f2h(a.y); o[2] = f2h(a.z); o[3] = f2h(a.w);
  o[4] = f2h(v.x); o[5] = f2h(v.y); o[6] = f2h(v.z); o[7] = f2h(v.w);
  *(bf16x8*)(d + i) = o;
  if (b == 0) {  // bias concat: 256 thr x 8 f32 = 2048
    const int j = threadIdx.x * 8;
#pragma unroll
    for (int k = 0; k < 8; ++k) {
      const int jj = j + k;
      bc[jj] = (jj < 1024) ? thb[jj] : phb[jj - 1024];
    }
  }
}

// one block per row of 4096 f16 scores; fp32 softmax; in-place f16 probs
__global__ __launch_bounds__(256) void softmax_rows(short* __restrict__ S) {
  const size_t row = blockIdx.x;
  short* rp = S + row * 4096;
  const int tid = threadIdx.x;
  const int lane = tid & 63, wid = tid >> 6;
  float v[16];
#pragma unroll
  for (int c = 0; c < 2; c++) {
    bf16x8 xv = *(const bf16x8*)(rp + (c * 256 + tid) * 8);
#pragma unroll
    for (int j = 0; j < 8; j++) v[c * 8 + j] = h2f(xv[j]);
  }
  float m = v[0];
#pragma unroll
  for (int i = 1; i < 16; i++) m = fmaxf(m, v[i]);
#pragma unroll
  for (int off = 32; off >= 1; off >>= 1) m = fmaxf(m, __shfl_xor(m, off));
  __shared__ float red[8];
  if (lane == 0) red[wid] = m;
  __syncthreads();
  m = fmaxf(fmaxf(red[0], red[1]), fmaxf(red[2], red[3]));
  float s = 0.f;
#pragma unroll
  for (int i = 0; i < 16; i++) {
    v[i] = __expf(v[i] - m);
    s += v[i];
  }
#pragma unroll
  for (int off = 32; off >= 1; off >>= 1) s += __shfl_xor(s, off);
  if (lane == 0) red[4 + wid] = s;
  __syncthreads();
  s = (red[4] + red[5]) + (red[6] + red[7]);
  const float rs = 1.0f / s;
#pragma unroll
  for (int c = 0; c < 2; c++) {
    bf16x8 o;
#pragma unroll
    for (int j = 0; j < 8; j++) o[j] = f2h(v[c * 8 + j] * rs);
    *(bf16x8*)(rp + (c * 256 + tid) * 8) = o;
  }
}

extern "C" void kernel_launch(void* const* d_in, const int* in_sizes, int n_in,
                              void* d_out, int out_size, void* d_ws,
                              size_t ws_size, hipStream_t stream) {
  const float* x   = (const float*)d_in[0];
  const float* thw = (const float*)d_in[1];
  const float* thb = (const float*)d_in[2];
  const float* phw = (const float*)d_in[3];
  const float* phb = (const float*)d_in[4];
  const float* gw  = (const float*)d_in[5];
  const float* gbi = (const float*)d_in[6];
  const float* Ww  = (const float*)d_in[7];
  const float* Wb  = (const float*)d_in[8];
  float* out = (float*)d_out;

  // B=4, N=4096, D=2048, E=1024.  ws footprint 184,557,568 B (L3-friendly;
  // r19 showed expanding to 251 MB regresses — aliased layout kept).
  char* ws = (char*)d_ws;
  short* xf   = (short*)(ws);                // 67,108,864 B (16384x2048 f16)
  short* wcat = (short*)(ws + 67108864);     //  8,388,608 B (theta|phi 2048x2048)
  short* gwb  = (short*)(ws + 75497472);     //  4,194,304 B (1024x2048)
  short* wWb  = (short*)(ws + 79691776);     //  4,194,304 B (2048x1024)
  float* bc   = (float*)(ws + 83886080);     //  8,192 B (theta_b|phi_b)
  short* tpf  = (short*)(ws + 83894272);     // 67,108,864 B (theta|phi; later y)
  short* gT   = (short*)(ws + 151003136);    // 33,554,432 B (4x1024x4096)
  short* sc   = (short*)(ws);                // 67,108,864 B (2x4096x4096, over xf)

  // 1) fp32 -> f16 conversions (x big pass + single merged weight pass)
  cvt_f32_f16<<<16384, 256, 0, stream>>>(x, xf, 33554432);
  cvt_weights<<<4096, 256, 0, stream>>>(thw, phw, gw, Ww, wcat, gwb, wWb, thb,
                                        phb, bc);

  // 2) proj: [theta|phi] = x @ wcat^T + bias   (16384 x 2048, K=2048)
  gemm256<4, 2048, 1, 1, 0><<<dim3(8, 64, 1), 512, 0, stream>>>(
      xf, 2048, 0L, wcat, 2048, 0L, tpf, 2048, 0L, bc, nullptr, 0L);

  // 3) gT[b] = g_w @ x_b^T + g_b[row]   (1024 x 4096 per batch, K=2048)
  gemm256<4, 2048, 1, 2, 0><<<dim3(16, 4, 4), 512, 0, stream>>>(
      gwb, 2048, 0L, xf, 2048, 8388608L, gT, 4096, 4194304L, gbi, nullptr, 0L);

  // 4) per batch-PAIR p: scores(z=2) -> softmax -> y(z=2) -> z(z=2)
  //    sc pair overlays xf (dead after gT); y overwrites consumed theta/phi.
  for (int p = 0; p < 2; ++p) {
    const short* tp = tpf + (size_t)p * 16777216;
    gemm256<4, 1024, 1, 0, 0><<<dim3(16, 16, 2), 512, 0, stream>>>(
        tp, 2048, 8388608L, tp + 1024, 2048, 8388608L,
        sc, 4096, 16777216L, nullptr, nullptr, 0L);
    softmax_rows<<<8192, 256, 0, stream>>>(sc);
    short* yp = tpf + (size_t)p * 16777216;  // pair-p theta/phi now dead
    gemm256<2, 4096, 1, 0, 0><<<dim3(8, 16, 2), 512, 0, stream>>>(
        sc, 4096, 16777216L, gT + (size_t)p * 8388608, 4096, 4194304L,
        yp, 1024, 4194304L, nullptr, nullptr, 0L);
    gemm256<4, 1024, 0, 1, 1><<<dim3(8, 16, 2), 512, 0, stream>>>(
        yp, 1024, 4194304L, wWb, 1024, 0L,
        out + (size_t)p * 16777216, 2048, 8388608L,
        Wb, x + (size_t)p * 16777216, 8388608L);
  }
}